// Round 1
// baseline (100.557 us; speedup 1.0000x reference)
//
#include <hip/hip_runtime.h>

// Linear (kernelized) attention, N=8 L=S=8192 H=8 D=32, fp32.
// out = (Q'·(K'^T V)) / (Q'·Ksum + eps), Q'/K' = elu(x)+1.
// The /v_length and *v_length in the reference cancel exactly (2^13).

constexpr int N_ = 8, L_ = 8192, S_ = 8192, H_ = 8, D_ = 32;
constexpr int NH = N_ * H_;                  // 64 (n,h) pairs
constexpr int SPLIT = 32;                    // S-chunks per (n,h)
constexpr int CS = S_ / SPLIT;               // 256 rows per block
constexpr int TS = 32;                       // LDS tile rows
constexpr int PART_STRIDE = D_ * D_ + D_;    // 1024 KV + 32 Ksum = 1056
constexpr int LCH = 512;                     // L-chunk per phase-2 block
constexpr float EPS_ = 1e-6f;

__device__ __forceinline__ float fmap(float x) {
    // elu(x)+1  (alpha=1): x>0 ? x+1 : exp(x)
    return x > 0.0f ? x + 1.0f : __expf(x);
}

// ---------------- phase 1: partial KV (D x D) + Ksum per (n,h,s-chunk) -----
__global__ __launch_bounds__(256) void lin_attn_phase1(
        const float* __restrict__ Kg, const float* __restrict__ Vg,
        float* __restrict__ part) {
    const int blk = blockIdx.x;
    const int nh = blk / SPLIT;
    const int sc = blk % SPLIT;
    const int n = nh / H_, h = nh % H_;
    const int t = threadIdx.x;
    const int v  = t & 31;            // output column
    const int d4 = (t >> 5) << 2;     // output row quad base: 0,4,...,28
    const int lr = t >> 3;            // tile-load row 0..31
    const int lc = (t & 7) << 2;      // tile-load col {0,4,...,28}

    __shared__ float Kt[TS][D_];
    __shared__ float Vt[TS][D_];
    __shared__ float ksum_sh[D_];

    if (t < D_) ksum_sh[t] = 0.0f;

    float acc0 = 0.f, acc1 = 0.f, acc2 = 0.f, acc3 = 0.f;
    float kp0 = 0.f, kp1 = 0.f, kp2 = 0.f, kp3 = 0.f;

    const size_t base = (size_t)n * S_ * H_ * D_ + (size_t)h * D_;
    const int s0 = sc * CS;
    for (int ss = 0; ss < CS; ss += TS) {
        const size_t off = base + (size_t)(s0 + ss + lr) * (H_ * D_) + lc;
        const float4 kraw = *reinterpret_cast<const float4*>(Kg + off);
        const float4 vraw = *reinterpret_cast<const float4*>(Vg + off);
        float4 kf;
        kf.x = fmap(kraw.x); kf.y = fmap(kraw.y);
        kf.z = fmap(kraw.z); kf.w = fmap(kraw.w);
        kp0 += kf.x; kp1 += kf.y; kp2 += kf.z; kp3 += kf.w;
        __syncthreads();   // previous tile fully consumed
        *reinterpret_cast<float4*>(&Kt[lr][lc]) = kf;
        *reinterpret_cast<float4*>(&Vt[lr][lc]) = vraw;
        __syncthreads();
        #pragma unroll
        for (int r = 0; r < TS; ++r) {
            const float vv = Vt[r][v];                                   // stride-1, conflict-free
            const float4 kk = *reinterpret_cast<const float4*>(&Kt[r][d4]); // broadcast
            acc0 += kk.x * vv;
            acc1 += kk.y * vv;
            acc2 += kk.z * vv;
            acc3 += kk.w * vv;
        }
    }

    __syncthreads();
    atomicAdd(&ksum_sh[lc + 0], kp0);
    atomicAdd(&ksum_sh[lc + 1], kp1);
    atomicAdd(&ksum_sh[lc + 2], kp2);
    atomicAdd(&ksum_sh[lc + 3], kp3);
    __syncthreads();

    float* P = part + ((size_t)sc * NH + nh) * PART_STRIDE;
    P[(d4 + 0) * D_ + v] = acc0;
    P[(d4 + 1) * D_ + v] = acc1;
    P[(d4 + 2) * D_ + v] = acc2;
    P[(d4 + 3) * D_ + v] = acc3;
    if (t < D_) P[D_ * D_ + t] = ksum_sh[t];
}

// ---------------- reduce the SPLIT partials -------------------------------
__global__ __launch_bounds__(256) void lin_attn_reduce(
        const float* __restrict__ part, float* __restrict__ red) {
    const int i = blockIdx.x * 256 + threadIdx.x;
    if (i >= NH * PART_STRIDE) return;
    float s = 0.0f;
    #pragma unroll
    for (int sc = 0; sc < SPLIT; ++sc)
        s += part[(size_t)sc * (NH * PART_STRIDE) + i];
    red[i] = s;
}

// ---------------- phase 2: out = (Q'.KV) / (Q'.Ksum + eps) ----------------
__global__ __launch_bounds__(256) void lin_attn_phase2(
        const float* __restrict__ Qg, const float* __restrict__ red,
        float* __restrict__ outg) {
    constexpr int NLC = L_ / LCH;     // 16
    const int nh  = blockIdx.x / NLC;
    const int lcb = blockIdx.x % NLC;
    const int n = nh / H_, h = nh % H_;
    const int t = threadIdx.x;
    const int v  = t & 31;
    const int rb = t >> 5;            // 0..7
    const int r  = t >> 3;            // load row 0..31
    const int c  = (t & 7) << 2;      // load col

    __shared__ float Qt[TS][D_];

    // Pin this thread's KV column + Ksum in registers (static indexing only).
    float kv[D_];
    float ks[D_];
    {
        const float* W = red + (size_t)nh * PART_STRIDE;
        #pragma unroll
        for (int d = 0; d < D_; ++d) kv[d] = W[d * D_ + v];
        #pragma unroll
        for (int d = 0; d < D_; ++d) ks[d] = W[D_ * D_ + d];
    }

    const size_t base = (size_t)n * L_ * H_ * D_ + (size_t)h * D_;
    const int l0 = lcb * LCH;
    for (int step = 0; step < LCH; step += TS) {
        const float4 q4 = *reinterpret_cast<const float4*>(
            Qg + base + (size_t)(l0 + step + r) * (H_ * D_) + c);
        __syncthreads();   // previous Qt fully consumed
        float4 qf;
        qf.x = fmap(q4.x); qf.y = fmap(q4.y);
        qf.z = fmap(q4.z); qf.w = fmap(q4.w);
        *reinterpret_cast<float4*>(&Qt[r][c]) = qf;
        __syncthreads();
        #pragma unroll
        for (int rr = 0; rr < 4; ++rr) {
            const int row = (rr << 3) + rb;
            float acc = 0.0f, accz = 0.0f;
            #pragma unroll
            for (int d = 0; d < D_; ++d) {
                const float q = Qt[row][d];   // broadcast read
                acc  += q * kv[d];
                accz += q * ks[d];
            }
            outg[base + (size_t)(l0 + step + row) * (H_ * D_) + v] =
                acc / (accz + EPS_);
        }
    }
}

extern "C" void kernel_launch(void* const* d_in, const int* in_sizes, int n_in,
                              void* d_out, int out_size, void* d_ws, size_t ws_size,
                              hipStream_t stream) {
    const float* Q = (const float*)d_in[0];
    const float* K = (const float*)d_in[1];
    const float* V = (const float*)d_in[2];
    float* out  = (float*)d_out;
    float* part = (float*)d_ws;                                   // 32*64*1056 f32
    float* red  = part + (size_t)SPLIT * NH * PART_STRIDE;        // 64*1056 f32

    lin_attn_phase1<<<NH * SPLIT, 256, 0, stream>>>(K, V, part);
    lin_attn_reduce<<<(NH * PART_STRIDE + 255) / 256, 256, 0, stream>>>(part, red);
    lin_attn_phase2<<<NH * (L_ / LCH), 256, 0, stream>>>(Q, red, out);
}

// Round 2
// 92.646 us; speedup vs baseline: 1.0854x; 1.0854x over previous
//
#include <hip/hip_runtime.h>

// Linear (kernelized) attention, N=8 L=S=8192 H=8 D=32, fp32.
// out = (Q'·(K'^T V)) / (Q'·Ksum + eps), Q'/K' = elu(x)+1.
// The /v_length and *v_length in the reference cancel exactly (2^13).

constexpr int N_ = 8, L_ = 8192, S_ = 8192, H_ = 8, D_ = 32;
constexpr int NH = N_ * H_;                  // 64 (n,h) pairs
constexpr int SPLIT = 32;                    // S-chunks per (n,h)
constexpr int CS = S_ / SPLIT;               // 256 rows per block
constexpr int TS = 64;                       // LDS tile rows
constexpr int PART_STRIDE = D_ * D_ + D_;    // 1024 KV + 32 Ksum = 1056
constexpr int LCH = 512;                     // L-chunk per phase-2 block
constexpr float EPS_ = 1e-6f;

__device__ __forceinline__ float fmap(float x) {
    // elu(x)+1  (alpha=1): x>0 ? x+1 : exp(x)
    return x > 0.0f ? x + 1.0f : __expf(x);
}

// ---------------- phase 1: partial KV (D x D) + Ksum per (n,h,s-chunk) -----
// 8x4 register blocking: thread owns KV[d0..d0+7][v0..v0+3]; 8 subgroups of
// 32 threads each cover 8 rows of a 64-row tile. 3 ds_read_b128 per 32 FMA.
__global__ __launch_bounds__(256, 4) void lin_attn_phase1(
        const float* __restrict__ Kg, const float* __restrict__ Vg,
        float* __restrict__ part) {
    const int blk = blockIdx.x;
    const int nh = blk / SPLIT;
    const int sc = blk % SPLIT;
    const int n = nh / H_, h = nh % H_;
    const int t = threadIdx.x;
    const int g  = t >> 5;            // subgroup 0..7
    const int j  = t & 31;
    const int d0 = (j >> 3) << 3;     // 0,8,16,24
    const int v0 = (j & 7) << 2;      // 0,4,...,28
    const int srow = t >> 3;          // staging row 0..31
    const int scol = (t & 7) << 2;    // staging col {0,4,...,28}

    __shared__ __align__(16) float smem[8 * 1024];   // 32KB: tiles, then reduction
    __shared__ float ksum_sh[D_];
    float (*Kt)[D_] = (float(*)[D_])smem;            // [64][32] = 8KB
    float (*Vt)[D_] = (float(*)[D_])(smem + TS * D_);// [64][32] = 8KB

    if (t < D_) ksum_sh[t] = 0.0f;

    float acc[8][4];
    #pragma unroll
    for (int a = 0; a < 8; ++a)
        #pragma unroll
        for (int b = 0; b < 4; ++b) acc[a][b] = 0.0f;
    float kp0 = 0.f, kp1 = 0.f, kp2 = 0.f, kp3 = 0.f;

    const size_t base = (size_t)n * S_ * H_ * D_ + (size_t)h * D_;
    const int s0 = sc * CS;
    for (int ss = 0; ss < CS; ss += TS) {
        const size_t o0 = base + (size_t)(s0 + ss + srow) * (H_ * D_) + scol;
        const size_t o1 = base + (size_t)(s0 + ss + srow + 32) * (H_ * D_) + scol;
        float4 k0 = *reinterpret_cast<const float4*>(Kg + o0);
        float4 k1 = *reinterpret_cast<const float4*>(Kg + o1);
        const float4 va = *reinterpret_cast<const float4*>(Vg + o0);
        const float4 vb = *reinterpret_cast<const float4*>(Vg + o1);
        k0.x = fmap(k0.x); k0.y = fmap(k0.y); k0.z = fmap(k0.z); k0.w = fmap(k0.w);
        k1.x = fmap(k1.x); k1.y = fmap(k1.y); k1.z = fmap(k1.z); k1.w = fmap(k1.w);
        kp0 += k0.x + k1.x; kp1 += k0.y + k1.y;
        kp2 += k0.z + k1.z; kp3 += k0.w + k1.w;
        __syncthreads();   // previous tile fully consumed
        *reinterpret_cast<float4*>(&Kt[srow     ][scol]) = k0;
        *reinterpret_cast<float4*>(&Kt[srow + 32][scol]) = k1;
        *reinterpret_cast<float4*>(&Vt[srow     ][scol]) = va;
        *reinterpret_cast<float4*>(&Vt[srow + 32][scol]) = vb;
        __syncthreads();
        #pragma unroll
        for (int r = 0; r < 8; ++r) {
            const int row = (g << 3) + r;
            const float4 ka = *reinterpret_cast<const float4*>(&Kt[row][d0]);
            const float4 kb = *reinterpret_cast<const float4*>(&Kt[row][d0 + 4]);
            const float4 vv = *reinterpret_cast<const float4*>(&Vt[row][v0]);
            const float kd[8] = {ka.x, ka.y, ka.z, ka.w, kb.x, kb.y, kb.z, kb.w};
            const float vs[4] = {vv.x, vv.y, vv.z, vv.w};
            #pragma unroll
            for (int a = 0; a < 8; ++a)
                #pragma unroll
                for (int b = 0; b < 4; ++b)
                    acc[a][b] += kd[a] * vs[b];
        }
    }

    // ---- in-block reduction of the 8 subgroup partials (deterministic) ----
    __syncthreads();               // tiles no longer needed; overlay red[]
    float* red = smem;             // [8][1024]
    #pragma unroll
    for (int a = 0; a < 8; ++a) {
        const float4 w = make_float4(acc[a][0], acc[a][1], acc[a][2], acc[a][3]);
        *reinterpret_cast<float4*>(&red[(size_t)g * 1024 + (d0 + a) * D_ + v0]) = w;
    }
    atomicAdd(&ksum_sh[scol + 0], kp0);
    atomicAdd(&ksum_sh[scol + 1], kp1);
    atomicAdd(&ksum_sh[scol + 2], kp2);
    atomicAdd(&ksum_sh[scol + 3], kp3);
    __syncthreads();

    float* P = part + ((size_t)sc * NH + nh) * PART_STRIDE;
    const int i4 = t << 2;         // 0,4,...,1020
    float4 s = make_float4(0.f, 0.f, 0.f, 0.f);
    #pragma unroll
    for (int g2 = 0; g2 < 8; ++g2) {
        const float4 rr = *reinterpret_cast<const float4*>(&red[(size_t)g2 * 1024 + i4]);
        s.x += rr.x; s.y += rr.y; s.z += rr.z; s.w += rr.w;
    }
    *reinterpret_cast<float4*>(&P[i4]) = s;
    if (t < D_) P[D_ * D_ + t] = ksum_sh[t];
}

// ---------------- reduce the SPLIT partials -------------------------------
__global__ __launch_bounds__(256) void lin_attn_reduce(
        const float* __restrict__ part, float* __restrict__ red) {
    const int i = blockIdx.x * 256 + threadIdx.x;
    if (i >= NH * PART_STRIDE) return;
    float s = 0.0f;
    #pragma unroll
    for (int sc = 0; sc < SPLIT; ++sc)
        s += part[(size_t)sc * (NH * PART_STRIDE) + i];
    red[i] = s;
}

// ---------------- phase 2: out = (Q'.KV) / (Q'.Ksum + eps) ----------------
__global__ __launch_bounds__(256) void lin_attn_phase2(
        const float* __restrict__ Qg, const float* __restrict__ red,
        float* __restrict__ outg) {
    constexpr int QTS = 32;           // Q tile rows
    constexpr int NLC = L_ / LCH;     // 16
    const int nh  = blockIdx.x / NLC;
    const int lcb = blockIdx.x % NLC;
    const int n = nh / H_, h = nh % H_;
    const int t = threadIdx.x;
    const int v  = t & 31;
    const int rb = t >> 5;            // 0..7
    const int r  = t >> 3;            // load row 0..31
    const int c  = (t & 7) << 2;      // load col

    __shared__ float Qt[QTS][D_];

    // Pin this thread's KV column + Ksum in registers (static indexing only).
    float kv[D_];
    float ks[D_];
    {
        const float* W = red + (size_t)nh * PART_STRIDE;
        #pragma unroll
        for (int d = 0; d < D_; ++d) kv[d] = W[d * D_ + v];
        #pragma unroll
        for (int d = 0; d < D_; ++d) ks[d] = W[D_ * D_ + d];
    }

    const size_t base = (size_t)n * L_ * H_ * D_ + (size_t)h * D_;
    const int l0 = lcb * LCH;
    for (int step = 0; step < LCH; step += QTS) {
        const float4 q4 = *reinterpret_cast<const float4*>(
            Qg + base + (size_t)(l0 + step + r) * (H_ * D_) + c);
        __syncthreads();   // previous Qt fully consumed
        float4 qf;
        qf.x = fmap(q4.x); qf.y = fmap(q4.y);
        qf.z = fmap(q4.z); qf.w = fmap(q4.w);
        *reinterpret_cast<float4*>(&Qt[r][c]) = qf;
        __syncthreads();
        #pragma unroll
        for (int rr = 0; rr < 4; ++rr) {
            const int row = (rr << 3) + rb;
            float acc = 0.0f, accz = 0.0f;
            #pragma unroll
            for (int d = 0; d < D_; ++d) {
                const float q = Qt[row][d];   // 2-address broadcast read
                acc  += q * kv[d];
                accz += q * ks[d];
            }
            outg[base + (size_t)(l0 + step + row) * (H_ * D_) + v] =
                acc / (accz + EPS_);
        }
    }
}

extern "C" void kernel_launch(void* const* d_in, const int* in_sizes, int n_in,
                              void* d_out, int out_size, void* d_ws, size_t ws_size,
                              hipStream_t stream) {
    const float* Q = (const float*)d_in[0];
    const float* K = (const float*)d_in[1];
    const float* V = (const float*)d_in[2];
    float* out  = (float*)d_out;
    float* part = (float*)d_ws;                                   // 32*64*1056 f32
    float* red  = part + (size_t)SPLIT * NH * PART_STRIDE;        // 64*1056 f32

    lin_attn_phase1<<<NH * SPLIT, 256, 0, stream>>>(K, V, part);
    lin_attn_reduce<<<(NH * PART_STRIDE + 255) / 256, 256, 0, stream>>>(part, red);
    lin_attn_phase2<<<NH * (L_ / LCH), 256, 0, stream>>>(Q, red, out);
}